// Round 11
// baseline (179.354 us; speedup 1.0000x reference)
//
#include <hip/hip_runtime.h>
#include <hip/hip_bf16.h>
#include <math.h>

typedef short bf16x8 __attribute__((ext_vector_type(8)));
typedef float f32x4 __attribute__((ext_vector_type(4)));
typedef unsigned short u16;
typedef unsigned int u32;

#define NH 8
#define BB 2
#define NQ 1024
#define NK 2048
#define NSPLIT 4
#define M2CONST 6.4921250  // 4.5 * log2(e), folded into poly c0
#define SC2 0.18033688f    // 0.125 * log2(e)
#define LS 68              // LDS stride (u16): b128 reads = 2-way max = free

#define MFMA16(a, b, c) __builtin_amdgcn_mfma_f32_16x16x32_bf16(a, b, c, 0, 0, 0)

// Chebyshev nodes in u = d^2 over [0,256], u_i = 128 + 128*cos(pi*(2i+1)/12)
__device__ __constant__ double XN_D[6] = {251.63850576500074, 218.50966799187810,
                                          161.12883777312265, 94.871162226877350,
                                          37.490330081221910, 4.3614942349992570};

// fast RNE bf16 round: result in bits [31:16] (valid for finite values)
static __device__ __forceinline__ u32 bfr(float x) {
  u32 u = __builtin_bit_cast(u32, x);
  return u + 0x7FFFu + ((u >> 16) & 1u);
}
static __device__ __forceinline__ u32 pk2(float lo, float hi) {
  return (bfr(lo) >> 16) | (bfr(hi) & 0xFFFF0000u);
}
static __device__ __forceinline__ u16 bfs(float x) { return (u16)(bfr(x) >> 16); }

// ==== setup: weight tcasts + poly fit + keg + input bf16 casts =============
// grid 1809: [0,256) tcast; 256 poly; [257,273) keg; [273,1809) input casts
__global__ __launch_bounds__(256) void setup_kernel(
    const float* __restrict__ Wq, const float* __restrict__ Wk,
    const float* __restrict__ Wv, const float* __restrict__ Wo,
    u16* __restrict__ Tq, u16* __restrict__ Tk,
    u16* __restrict__ Tv, u16* __restrict__ To,
    const float* __restrict__ W1, const float* __restrict__ b1,
    const float* __restrict__ W2, const float* __restrict__ b2,
    float* __restrict__ polyc,
    const float* __restrict__ kc, u16* __restrict__ keg,
    const float* __restrict__ q_in, const float* __restrict__ kv_in,
    u16* __restrict__ qb, u16* __restrict__ kvb) {
  const int blk = blockIdx.x, t = threadIdx.x;
  if (blk >= 273) {
    int gi = (blk - 273) * 256 + t;
    const float* src; u16* dst; size_t off;
    if (gi < 131072) { src = q_in; dst = qb; off = (size_t)gi * 8; }
    else             { src = kv_in; dst = kvb; off = (size_t)(gi - 131072) * 8; }
    float4 a = *(const float4*)(src + off);
    float4 b = *(const float4*)(src + off + 4);
    uint4 o;
    o.x = pk2(a.x, a.y); o.y = pk2(a.z, a.w);
    o.z = pk2(b.x, b.y); o.w = pk2(b.z, b.w);
    *(uint4*)(dst + off) = o;
  } else if (blk < 256) {
    __shared__ u16 tile[64][65];
    const float* W; u16* Wt;
    switch (blk >> 6) {
      case 0: W = Wq; Wt = Tq; break;
      case 1: W = Wk; Wt = Tk; break;
      case 2: W = Wv; Wt = Tv; break;
      default: W = Wo; Wt = To; break;
    }
    const int rem = blk & 63;
    const int k0 = (rem >> 3) * 64, n0 = (rem & 7) * 64;
    const int r = t >> 4, c4 = (t & 15) * 4;
    #pragma unroll
    for (int p = 0; p < 4; p++) {
      int row = p * 16 + r;
      float4 v = *(const float4*)&W[(size_t)(k0 + row) * 512 + n0 + c4];
      tile[row][c4 + 0] = bfs(v.x);
      tile[row][c4 + 1] = bfs(v.y);
      tile[row][c4 + 2] = bfs(v.z);
      tile[row][c4 + 3] = bfs(v.w);
    }
    __syncthreads();
    #pragma unroll
    for (int p = 0; p < 4; p++) {
      int n = p * 16 + r;
      u16 u0 = tile[c4 + 0][n], u1 = tile[c4 + 1][n];
      u16 u2 = tile[c4 + 2][n], u3 = tile[c4 + 3][n];
      uint2 o;
      o.x = u0 | ((u32)u1 << 16);
      o.y = u2 | ((u32)u3 << 16);
      *(uint2*)&Wt[(size_t)(n0 + n) * 512 + k0 + c4] = o;
    }
  } else if (blk == 256) {
    __shared__ double fv[6][8];
    if (t < 48) {
      int i = t >> 3, h = t & 7;
      double x = sqrt(XN_D[i]);
      double acc = (double)b2[h];
      for (int r = 0; r < 64; r++) {
        double u = x * (double)W1[r] + (double)b1[r];
        double s = u / (1.0 + exp(-u));
        acc += s * (double)W2[r * 8 + h];
      }
      fv[i][h] = acc * 1.4426950408889634 - M2CONST;
    }
    __syncthreads();
    if (t < 8) {
      int h = t;
      double c[6];
      #pragma unroll
      for (int i = 0; i < 6; i++) c[i] = fv[i][h];
      for (int k = 1; k < 6; k++)
        for (int i = 5; i >= k; i--)
          c[i] = (c[i] - c[i - 1]) / (XN_D[i] - XN_D[i - k]);
      double m[6] = {c[5], 0, 0, 0, 0, 0};
      int deg = 0;
      for (int i = 4; i >= 0; i--) {
        double np[6] = {};
        for (int j = deg; j >= 0; j--) np[j + 1] += m[j];
        for (int j = 0; j <= deg; j++) np[j] -= XN_D[i] * m[j];
        np[0] += c[i];
        deg++;
        for (int j = 0; j <= deg; j++) m[j] = np[j];
      }
      #pragma unroll
      for (int j = 0; j < 6; j++) polyc[h * 8 + j] = (float)m[j];
    }
  } else {
    int r = (blk - 257) * 256 + t;   // 0..4095 kv rows
    float kx = kc[(size_t)r * 3], ky = kc[(size_t)r * 3 + 1], kz = kc[(size_t)r * 3 + 2];
    uint4 o;
    o.x = pk2(-2.0f * kx, -2.0f * ky);
    o.y = pk2(-2.0f * kz, 1.0f);
    o.z = (u32)bfs(kx * kx + ky * ky + kz * kz);
    o.w = 0;
    *(uint4*)&keg[(size_t)r * 8] = o;
  }
}

// ======= fused Q/K/V projection, all-bf16 inputs, BK=64 ====================
// grid (96, 8): x<32 -> Q rows (Wq); x>=32 -> KV rows (Wk + Wv fused)
__global__ __launch_bounds__(256) void gemm_qkv(
    const u16* __restrict__ qb, const u16* __restrict__ kvb,
    const u16* __restrict__ Wqt, const u16* __restrict__ Wkt,
    const u16* __restrict__ Wvt, u16* __restrict__ Qp,
    u16* __restrict__ Kp, u16* __restrict__ Vtp) {
  __shared__ u16 As[64 * LS];
  __shared__ u16 Bs[64 * LS];
  __shared__ u16 Bs2[64 * LS];
  const int t = threadIdx.x;
  const int w = t >> 6, l = t & 63, g = l >> 4, li = l & 15;
  const int bx = blockIdx.x;
  const bool isQ = bx < 32;
  const int m0 = (isQ ? bx : bx - 32) * 64, n0 = blockIdx.y * 64;
  const u16* A = isQ ? qb : kvb;
  const u16* B1 = isQ ? Wqt : Wkt;
  const int ms = (w & 1) * 32, ns = (w >> 1) * 32;
  f32x4 acc[2][2] = {}, accV[2][2] = {};

  for (int kt = 0; kt < 512; kt += 64) {
    bf16x8 av[2], bk[2], bv2[2];
    #pragma unroll
    for (int p = 0; p < 2; p++) {
      int f = p * 256 + t, r = f >> 3, c8 = (f & 7) * 8;
      av[p] = *(const bf16x8*)&A[(size_t)(m0 + r) * 512 + kt + c8];
      bk[p] = *(const bf16x8*)&B1[(size_t)(n0 + r) * 512 + kt + c8];
    }
    if (!isQ) {
      #pragma unroll
      for (int p = 0; p < 2; p++) {
        int f = p * 256 + t, r = f >> 3, c8 = (f & 7) * 8;
        bv2[p] = *(const bf16x8*)&Wvt[(size_t)(n0 + r) * 512 + kt + c8];
      }
    }
    __syncthreads();
    #pragma unroll
    for (int p = 0; p < 2; p++) {
      int f = p * 256 + t, r = f >> 3, c8 = (f & 7) * 8;
      *(bf16x8*)&As[r * LS + c8] = av[p];
      *(bf16x8*)&Bs[r * LS + c8] = bk[p];
    }
    if (!isQ) {
      #pragma unroll
      for (int p = 0; p < 2; p++) {
        int f = p * 256 + t, r = f >> 3, c8 = (f & 7) * 8;
        *(bf16x8*)&Bs2[r * LS + c8] = bv2[p];
      }
    }
    __syncthreads();
    #pragma unroll
    for (int ks = 0; ks < 2; ks++) {
      bf16x8 a0 = *(const bf16x8*)&As[(ms + li) * LS + ks * 32 + g * 8];
      bf16x8 a1 = *(const bf16x8*)&As[(ms + 16 + li) * LS + ks * 32 + g * 8];
      bf16x8 k0 = *(const bf16x8*)&Bs[(ns + li) * LS + ks * 32 + g * 8];
      bf16x8 k1 = *(const bf16x8*)&Bs[(ns + 16 + li) * LS + ks * 32 + g * 8];
      acc[0][0] = MFMA16(a0, k0, acc[0][0]);
      acc[0][1] = MFMA16(a0, k1, acc[0][1]);
      acc[1][0] = MFMA16(a1, k0, acc[1][0]);
      acc[1][1] = MFMA16(a1, k1, acc[1][1]);
      if (!isQ) {
        bf16x8 v0 = *(const bf16x8*)&Bs2[(ns + li) * LS + ks * 32 + g * 8];
        bf16x8 v1 = *(const bf16x8*)&Bs2[(ns + 16 + li) * LS + ks * 32 + g * 8];
        accV[0][0] = MFMA16(a0, v0, accV[0][0]);
        accV[0][1] = MFMA16(a0, v1, accV[0][1]);
        accV[1][0] = MFMA16(a1, v0, accV[1][0]);
        accV[1][1] = MFMA16(a1, v1, accV[1][1]);
      }
    }
  }
  #pragma unroll
  for (int mi = 0; mi < 2; mi++) {
    #pragma unroll
    for (int ni = 0; ni < 2; ni++) {
      int row = m0 + ms + mi * 16 + 4 * g;
      int col = n0 + ns + ni * 16 + li;
      f32x4 vk = acc[mi][ni];
      if (isQ) {
        #pragma unroll
        for (int r = 0; r < 4; r++) Qp[(size_t)(row + r) * 512 + col] = bfs(vk[r]);
      } else {
        #pragma unroll
        for (int r = 0; r < 4; r++) Kp[(size_t)(row + r) * 512 + col] = bfs(vk[r]);
        f32x4 vv = accV[mi][ni];
        int bb = row >> 11, j = row & 2047;
        int hh = col >> 6, d = col & 63;
        uint2 o;
        o.x = pk2(vv[0], vv[1]);
        o.y = pk2(vv[2], vv[3]);
        *(uint2*)&Vtp[((size_t)((bb * 8 + hh) * 64 + d)) * 2048 + j] = o;
      }
    }
  }
}

// ---- barrier-free flash attention: frags direct from global (L1-shared) ---
// grid (64, 8, 2): x = qt*4 + split (NSPLIT=4); block = 4 waves = 4 q-tiles
// of the SAME (b,h,split) -> identical K/V addresses -> L1 serves 3 of 4.
// NO __syncthreads anywhere; only wave-private P roundtrip in LDS.
__global__ __launch_bounds__(256, 4) void attn_kernel(
    const u16* __restrict__ Qb, const u16* __restrict__ Kb,
    const u16* __restrict__ Vt, const float* __restrict__ qc,
    const u16* __restrict__ keg, const float* __restrict__ polyc,
    float* __restrict__ Op, float* __restrict__ Lp) {
  __shared__ u16 Pl[64 * LS];   // wave w owns rows [w*16, w*16+16)

  const int t = threadIdx.x;
  const int w = t >> 6, l = t & 63, g = l >> 4, li = l & 15;
  const int qt = blockIdx.x >> 2, sidx = blockIdx.x & 3;
  const int h = blockIdx.y, b = blockIdx.z;

  const float c0 = polyc[h * 8 + 0], c1 = polyc[h * 8 + 1];
  const float c2 = polyc[h * 8 + 2], c3 = polyc[h * 8 + 3];
  const float c4 = polyc[h * 8 + 4], c5 = polyc[h * 8 + 5];

  const int qrow = qt * 64 + w * 16 + li;
  const size_t qg = (size_t)b * NQ + qrow;
  bf16x8 qf0 = *(const bf16x8*)&Qb[qg * 512 + h * 64 + g * 8];
  bf16x8 qf1 = *(const bf16x8*)&Qb[qg * 512 + h * 64 + 32 + g * 8];
  float qx = qc[qg * 3], qy = qc[qg * 3 + 1], qz = qc[qg * 3 + 2];
  bf16x8 qe = {};
  if (g == 0) {
    qe[0] = (short)bfs(qx);
    qe[1] = (short)bfs(qy);
    qe[2] = (short)bfs(qz);
    qe[3] = (short)bfs(qx * qx + qy * qy + qz * qz);
    qe[4] = (short)bfs(1.0f);
  }

  f32x4 oacc[4] = {};
  float lacc = 0.0f;

  const u16* Kg = Kb + (size_t)b * NK * 512 + h * 64;
  const u16* Vg = Vt + (size_t)((b * 8 + h) * 64) * 2048;
  const u16* keg_b = keg + (size_t)b * NK * 8;
  const int jb0 = sidx * (NK / NSPLIT);

  for (int it = 0; it < NK / NSPLIT / 64; it++) {
    const int jbase = jb0 + it * 64;

    // S^T tiles + d^2 via MFMA; K A-frags read directly from global
    #pragma unroll
    for (int j4 = 0; j4 < 4; j4++) {
      const u16* krow = &Kg[(size_t)(jbase + j4 * 16 + li) * 512 + g * 8];
      bf16x8 ka0 = *(const bf16x8*)krow;
      bf16x8 ka1 = *(const bf16x8*)(krow + 32);
      f32x4 z = {};
      f32x4 s0 = MFMA16(ka0, qf0, z);
      f32x4 sac = MFMA16(ka1, qf1, s0);
      bf16x8 ke = {};
      if (g == 0)
        ke = *(const bf16x8*)&keg_b[(size_t)(jbase + j4 * 16 + li) * 8];
      f32x4 dac = MFMA16(ke, qe, z);

      float p[4];
      #pragma unroll
      for (int r = 0; r < 4; r++) {
        float u = fminf(dac[r], 256.0f);
        float gp = fmaf(fmaf(fmaf(fmaf(fmaf(c5, u, c4), u, c3), u, c2), u, c1), u, c0);
        p[r] = __builtin_amdgcn_exp2f(fmaf(sac[r], SC2, gp));
      }
      lacc += (p[0] + p[1]) + (p[2] + p[3]);
      uint2 pv;
      pv.x = pk2(p[0], p[1]);
      pv.y = pk2(p[2], p[3]);
      *(uint2*)&Pl[(w * 16 + li) * LS + j4 * 16 + g * 4] = pv;
    }

    // PV: P via wave-local LDS roundtrip; V B-frags direct from global
    bf16x8 pf0 = *(const bf16x8*)&Pl[(w * 16 + li) * LS + g * 8];
    bf16x8 pf1 = *(const bf16x8*)&Pl[(w * 16 + li) * LS + 32 + g * 8];
    #pragma unroll
    for (int dt = 0; dt < 4; dt++) {
      const u16* vrow = &Vg[(size_t)(dt * 16 + li) * 2048 + jbase + g * 8];
      bf16x8 v0 = *(const bf16x8*)vrow;
      bf16x8 v1 = *(const bf16x8*)(vrow + 32);
      oacc[dt] = MFMA16(pf0, v0, oacc[dt]);
      oacc[dt] = MFMA16(pf1, v1, oacc[dt]);
    }
  }

  float lf = lacc;
  lf += __shfl_xor(lf, 16);
  lf += __shfl_xor(lf, 32);

  const size_t obase =
      ((size_t)(sidx * 16 + b * 8 + h) * 1024 + qt * 64 + w * 16) * 64;
  #pragma unroll
  for (int dt = 0; dt < 4; dt++)
    #pragma unroll
    for (int r = 0; r < 4; r++)
      Op[obase + (size_t)(4 * g + r) * 64 + dt * 16 + li] = oacc[dt][r];
  if (g == 0)
    Lp[(size_t)(sidx * 16 + b * 8 + h) * 1024 + qt * 64 + w * 16 + li] = lf;
}

// ---------------- combine split partials, normalize, write bf16 AO ---------
__global__ __launch_bounds__(256) void combine_kernel(const float* __restrict__ Op,
                                                      const float* __restrict__ Lp,
                                                      u16* __restrict__ AOb) {
  int tid = blockIdx.x * 256 + threadIdx.x;   // 262144 total
  int d4 = tid & 15, rh = tid >> 4;
  int bh = rh >> 10, qrow = rh & 1023;
  f32x4 o = {};
  float lsum = 0.0f;
  #pragma unroll
  for (int s = 0; s < NSPLIT; s++) {
    f32x4 v = *(const f32x4*)&Op[((size_t)(s * 16 + bh) * 1024 + qrow) * 64 + d4 * 4];
    o += v;
    lsum += Lp[(size_t)(s * 16 + bh) * 1024 + qrow];
  }
  float inv = __builtin_amdgcn_rcpf(lsum);
  uint2 pk;
  pk.x = pk2(o[0] * inv, o[1] * inv);
  pk.y = pk2(o[2] * inv, o[3] * inv);
  *(uint2*)&AOb[((size_t)(bh >> 3) * NQ + qrow) * 512 + (bh & 7) * 64 + d4 * 4] = pk;
}

// ---------------- bf16 MFMA GEMM (Wo pass), TM=32, fp32 out ----------------
__global__ __launch_bounds__(256) void gemm_wo(const u16* __restrict__ A,
                                               const u16* __restrict__ Bt,
                                               float* __restrict__ C) {
  __shared__ u16 As[32 * LS];
  __shared__ u16 Bs[64 * LS];
  const int t = threadIdx.x;
  const int w = t >> 6, l = t & 63, g = l >> 4, li = l & 15;
  const int m0 = blockIdx.x * 32, n0 = blockIdx.y * 64;
  const int ms = (w & 1) * 16, ns = (w >> 1) * 32;
  f32x4 acc[2] = {};
  for (int kt = 0; kt < 512; kt += 64) {
    bf16x8 av, bv[2];
    {
      int r = t >> 3, c8 = (t & 7) * 8;
      av = *(const bf16x8*)&A[(size_t)(m0 + r) * 512 + kt + c8];
    }
    #pragma unroll
    for (int p = 0; p < 2; p++) {
      int f = p * 256 + t, r = f >> 3, c8 = (f & 7) * 8;
      bv[p] = *(const bf16x8*)&Bt[(size_t)(n0 + r) * 512 + kt + c8];
    }
    __syncthreads();
    {
      int r = t >> 3, c8 = (t & 7) * 8;
      *(bf16x8*)&As[r * LS + c8] = av;
    }
    #pragma unroll
    for (int p = 0; p < 2; p++) {
      int f = p * 256 + t, r = f >> 3, c8 = (f & 7) * 8;
      *(bf16x8*)&Bs[r * LS + c8] = bv[p];
    }
    __syncthreads();
    #pragma unroll
    for (int ks = 0; ks < 2; ks++) {
      bf16x8 af = *(const bf16x8*)&As[(ms + li) * LS + ks * 32 + g * 8];
      bf16x8 b0 = *(const bf16x8*)&Bs[(ns + li) * LS + ks * 32 + g * 8];
      bf16x8 b1 = *(const bf16x8*)&Bs[(ns + 16 + li) * LS + ks * 32 + g * 8];
      acc[0] = MFMA16(af, b0, acc[0]);
      acc[1] = MFMA16(af, b1, acc[1]);
    }
  }
  #pragma unroll
  for (int ni = 0; ni < 2; ni++) {
    f32x4 v = acc[ni];
    int row = m0 + ms + 4 * g;
    int col = n0 + ns + ni * 16 + li;
    #pragma unroll
    for (int r = 0; r < 4; r++) C[(size_t)(row + r) * 512 + col] = v[r];
  }
}

extern "C" void kernel_launch(void* const* d_in, const int* in_sizes, int n_in,
                              void* d_out, int out_size, void* d_ws, size_t ws_size,
                              hipStream_t stream) {
  const float* q_in      = (const float*)d_in[0];
  const float* kv_in     = (const float*)d_in[1];
  const float* q_coords  = (const float*)d_in[2];
  const float* kv_coords = (const float*)d_in[3];
  const float* Wq        = (const float*)d_in[4];
  const float* Wk        = (const float*)d_in[5];
  const float* Wv        = (const float*)d_in[6];
  const float* Wo        = (const float*)d_in[7];
  const float* W1        = (const float*)d_in[8];
  const float* b1        = (const float*)d_in[9];
  const float* W2        = (const float*)d_in[10];
  const float* b2        = (const float*)d_in[11];

  char* p = (char*)d_ws;
  u16* Wqt  = (u16*)p; p += (size_t)512 * 512 * 2;
  u16* Wkt  = (u16*)p; p += (size_t)512 * 512 * 2;
  u16* Wvt  = (u16*)p; p += (size_t)512 * 512 * 2;
  u16* Wot  = (u16*)p; p += (size_t)512 * 512 * 2;
  u16* qb   = (u16*)p; p += (size_t)2048 * 512 * 2;
  u16* kvb  = (u16*)p; p += (size_t)4096 * 512 * 2;
  u16* Qp   = (u16*)p; p += (size_t)2048 * 512 * 2;
  u16* Kp   = (u16*)p; p += (size_t)4096 * 512 * 2;
  u16* Vtp  = (u16*)p; p += (size_t)4096 * 512 * 2;
  u16* AOb  = (u16*)p; p += (size_t)2048 * 512 * 2;
  u16* keg  = (u16*)p; p += (size_t)4096 * 8 * 2;
  float* polyc = (float*)p; p += (size_t)64 * 4;
  p = (char*)(((size_t)p + 255) & ~(size_t)255);
  float* Opart = (float*)p; p += (size_t)NSPLIT * 16 * 1024 * 64 * 4;
  float* Lpart = (float*)p; p += (size_t)NSPLIT * 16 * 1024 * 4;

  setup_kernel<<<1809, 256, 0, stream>>>(Wq, Wk, Wv, Wo, Wqt, Wkt, Wvt, Wot,
                                         W1, b1, W2, b2, polyc, kv_coords, keg,
                                         q_in, kv_in, qb, kvb);
  gemm_qkv<<<dim3(96, 8), 256, 0, stream>>>(qb, kvb, Wqt, Wkt, Wvt,
                                            Qp, Kp, Vtp);
  attn_kernel<<<dim3(64, 8, 2), 256, 0, stream>>>(Qp, Kp, Vtp, q_coords, keg,
                                                  polyc, Opart, Lpart);
  combine_kernel<<<1024, 256, 0, stream>>>(Opart, Lpart, AOb);
  gemm_wo<<<dim3(64, 8), 256, 0, stream>>>(AOb, Wot, (float*)d_out);
}

// Round 12
// 143.878 us; speedup vs baseline: 1.2466x; 1.2466x over previous
//
#include <hip/hip_runtime.h>
#include <hip/hip_bf16.h>
#include <hip/hip_fp16.h>
#include <math.h>

typedef short bf16x8 __attribute__((ext_vector_type(8)));
typedef float f32x4 __attribute__((ext_vector_type(4)));
typedef unsigned short u16;
typedef unsigned int u32;

#define NH 8
#define BB 2
#define NQ 1024
#define NK 2048
#define NSPLIT 8
#define M2CONST 6.4921250  // 4.5 * log2(e), folded into poly c0
#define SC2 0.18033688f    // 0.125 * log2(e)
#define LS 68              // LDS stride (u16): b128 reads = 2-way max = free

#define MFMA16(a, b, c) __builtin_amdgcn_mfma_f32_16x16x32_bf16(a, b, c, 0, 0, 0)

// Chebyshev nodes in u = d^2 over [0,256], u_i = 128 + 128*cos(pi*(2i+1)/12)
__device__ __constant__ double XN_D[6] = {251.63850576500074, 218.50966799187810,
                                          161.12883777312265, 94.871162226877350,
                                          37.490330081221910, 4.3614942349992570};

// fast RNE bf16 round: result in bits [31:16] (valid for finite values)
static __device__ __forceinline__ u32 bfr(float x) {
  u32 u = __builtin_bit_cast(u32, x);
  return u + 0x7FFFu + ((u >> 16) & 1u);
}
static __device__ __forceinline__ u32 pk2(float lo, float hi) {
  return (bfr(lo) >> 16) | (bfr(hi) & 0xFFFF0000u);
}
static __device__ __forceinline__ u16 bfs(float x) { return (u16)(bfr(x) >> 16); }

// ==== setup: weight tcasts + poly fit + keg + input bf16 casts =============
// grid 1809: [0,256) tcast; 256 poly; [257,273) keg; [273,1809) input casts
__global__ __launch_bounds__(256) void setup_kernel(
    const float* __restrict__ Wq, const float* __restrict__ Wk,
    const float* __restrict__ Wv, const float* __restrict__ Wo,
    u16* __restrict__ Tq, u16* __restrict__ Tk,
    u16* __restrict__ Tv, u16* __restrict__ To,
    const float* __restrict__ W1, const float* __restrict__ b1,
    const float* __restrict__ W2, const float* __restrict__ b2,
    float* __restrict__ polyc,
    const float* __restrict__ kc, u16* __restrict__ keg,
    const float* __restrict__ q_in, const float* __restrict__ kv_in,
    u16* __restrict__ qb, u16* __restrict__ kvb) {
  const int blk = blockIdx.x, t = threadIdx.x;
  if (blk >= 273) {
    int gi = (blk - 273) * 256 + t;
    const float* src; u16* dst; size_t off;
    if (gi < 131072) { src = q_in; dst = qb; off = (size_t)gi * 8; }
    else             { src = kv_in; dst = kvb; off = (size_t)(gi - 131072) * 8; }
    float4 a = *(const float4*)(src + off);
    float4 b = *(const float4*)(src + off + 4);
    uint4 o;
    o.x = pk2(a.x, a.y); o.y = pk2(a.z, a.w);
    o.z = pk2(b.x, b.y); o.w = pk2(b.z, b.w);
    *(uint4*)(dst + off) = o;
  } else if (blk < 256) {
    __shared__ u16 tile[64][65];
    const float* W; u16* Wt;
    switch (blk >> 6) {
      case 0: W = Wq; Wt = Tq; break;
      case 1: W = Wk; Wt = Tk; break;
      case 2: W = Wv; Wt = Tv; break;
      default: W = Wo; Wt = To; break;
    }
    const int rem = blk & 63;
    const int k0 = (rem >> 3) * 64, n0 = (rem & 7) * 64;
    const int r = t >> 4, c4 = (t & 15) * 4;
    #pragma unroll
    for (int p = 0; p < 4; p++) {
      int row = p * 16 + r;
      float4 v = *(const float4*)&W[(size_t)(k0 + row) * 512 + n0 + c4];
      tile[row][c4 + 0] = bfs(v.x);
      tile[row][c4 + 1] = bfs(v.y);
      tile[row][c4 + 2] = bfs(v.z);
      tile[row][c4 + 3] = bfs(v.w);
    }
    __syncthreads();
    #pragma unroll
    for (int p = 0; p < 4; p++) {
      int n = p * 16 + r;
      u16 u0 = tile[c4 + 0][n], u1 = tile[c4 + 1][n];
      u16 u2 = tile[c4 + 2][n], u3 = tile[c4 + 3][n];
      uint2 o;
      o.x = u0 | ((u32)u1 << 16);
      o.y = u2 | ((u32)u3 << 16);
      *(uint2*)&Wt[(size_t)(n0 + n) * 512 + k0 + c4] = o;
    }
  } else if (blk == 256) {
    __shared__ double fv[6][8];
    if (t < 48) {
      int i = t >> 3, h = t & 7;
      double x = sqrt(XN_D[i]);
      double acc = (double)b2[h];
      for (int r = 0; r < 64; r++) {
        double u = x * (double)W1[r] + (double)b1[r];
        double s = u / (1.0 + exp(-u));
        acc += s * (double)W2[r * 8 + h];
      }
      fv[i][h] = acc * 1.4426950408889634 - M2CONST;
    }
    __syncthreads();
    if (t < 8) {
      int h = t;
      double c[6];
      #pragma unroll
      for (int i = 0; i < 6; i++) c[i] = fv[i][h];
      for (int k = 1; k < 6; k++)
        for (int i = 5; i >= k; i--)
          c[i] = (c[i] - c[i - 1]) / (XN_D[i] - XN_D[i - k]);
      double m[6] = {c[5], 0, 0, 0, 0, 0};
      int deg = 0;
      for (int i = 4; i >= 0; i--) {
        double np[6] = {};
        for (int j = deg; j >= 0; j--) np[j + 1] += m[j];
        for (int j = 0; j <= deg; j++) np[j] -= XN_D[i] * m[j];
        np[0] += c[i];
        deg++;
        for (int j = 0; j <= deg; j++) m[j] = np[j];
      }
      #pragma unroll
      for (int j = 0; j < 6; j++) polyc[h * 8 + j] = (float)m[j];
    }
  } else {
    int r = (blk - 257) * 256 + t;   // 0..4095 kv rows
    float kx = kc[(size_t)r * 3], ky = kc[(size_t)r * 3 + 1], kz = kc[(size_t)r * 3 + 2];
    uint4 o;
    o.x = pk2(-2.0f * kx, -2.0f * ky);
    o.y = pk2(-2.0f * kz, 1.0f);
    o.z = (u32)bfs(kx * kx + ky * ky + kz * kz);
    o.w = 0;
    *(uint4*)&keg[(size_t)r * 8] = o;
  }
}

// ======= fused Q/K/V projection, all-bf16 inputs, BK=64 ====================
// grid (96, 8): x<32 -> Q rows (Wq); x>=32 -> KV rows (Wk + Wv fused)
__global__ __launch_bounds__(256) void gemm_qkv(
    const u16* __restrict__ qb, const u16* __restrict__ kvb,
    const u16* __restrict__ Wqt, const u16* __restrict__ Wkt,
    const u16* __restrict__ Wvt, u16* __restrict__ Qp,
    u16* __restrict__ Kp, u16* __restrict__ Vtp) {
  __shared__ u16 As[64 * LS];
  __shared__ u16 Bs[64 * LS];
  __shared__ u16 Bs2[64 * LS];
  const int t = threadIdx.x;
  const int w = t >> 6, l = t & 63, g = l >> 4, li = l & 15;
  const int bx = blockIdx.x;
  const bool isQ = bx < 32;
  const int m0 = (isQ ? bx : bx - 32) * 64, n0 = blockIdx.y * 64;
  const u16* A = isQ ? qb : kvb;
  const u16* B1 = isQ ? Wqt : Wkt;
  const int ms = (w & 1) * 32, ns = (w >> 1) * 32;
  f32x4 acc[2][2] = {}, accV[2][2] = {};

  for (int kt = 0; kt < 512; kt += 64) {
    bf16x8 av[2], bk[2], bv2[2];
    #pragma unroll
    for (int p = 0; p < 2; p++) {
      int f = p * 256 + t, r = f >> 3, c8 = (f & 7) * 8;
      av[p] = *(const bf16x8*)&A[(size_t)(m0 + r) * 512 + kt + c8];
      bk[p] = *(const bf16x8*)&B1[(size_t)(n0 + r) * 512 + kt + c8];
    }
    if (!isQ) {
      #pragma unroll
      for (int p = 0; p < 2; p++) {
        int f = p * 256 + t, r = f >> 3, c8 = (f & 7) * 8;
        bv2[p] = *(const bf16x8*)&Wvt[(size_t)(n0 + r) * 512 + kt + c8];
      }
    }
    __syncthreads();
    #pragma unroll
    for (int p = 0; p < 2; p++) {
      int f = p * 256 + t, r = f >> 3, c8 = (f & 7) * 8;
      *(bf16x8*)&As[r * LS + c8] = av[p];
      *(bf16x8*)&Bs[r * LS + c8] = bk[p];
    }
    if (!isQ) {
      #pragma unroll
      for (int p = 0; p < 2; p++) {
        int f = p * 256 + t, r = f >> 3, c8 = (f & 7) * 8;
        *(bf16x8*)&Bs2[r * LS + c8] = bv2[p];
      }
    }
    __syncthreads();
    #pragma unroll
    for (int ks = 0; ks < 2; ks++) {
      bf16x8 a0 = *(const bf16x8*)&As[(ms + li) * LS + ks * 32 + g * 8];
      bf16x8 a1 = *(const bf16x8*)&As[(ms + 16 + li) * LS + ks * 32 + g * 8];
      bf16x8 k0 = *(const bf16x8*)&Bs[(ns + li) * LS + ks * 32 + g * 8];
      bf16x8 k1 = *(const bf16x8*)&Bs[(ns + 16 + li) * LS + ks * 32 + g * 8];
      acc[0][0] = MFMA16(a0, k0, acc[0][0]);
      acc[0][1] = MFMA16(a0, k1, acc[0][1]);
      acc[1][0] = MFMA16(a1, k0, acc[1][0]);
      acc[1][1] = MFMA16(a1, k1, acc[1][1]);
      if (!isQ) {
        bf16x8 v0 = *(const bf16x8*)&Bs2[(ns + li) * LS + ks * 32 + g * 8];
        bf16x8 v1 = *(const bf16x8*)&Bs2[(ns + 16 + li) * LS + ks * 32 + g * 8];
        accV[0][0] = MFMA16(a0, v0, accV[0][0]);
        accV[0][1] = MFMA16(a0, v1, accV[0][1]);
        accV[1][0] = MFMA16(a1, v0, accV[1][0]);
        accV[1][1] = MFMA16(a1, v1, accV[1][1]);
      }
    }
  }
  #pragma unroll
  for (int mi = 0; mi < 2; mi++) {
    #pragma unroll
    for (int ni = 0; ni < 2; ni++) {
      int row = m0 + ms + mi * 16 + 4 * g;
      int col = n0 + ns + ni * 16 + li;
      f32x4 vk = acc[mi][ni];
      if (isQ) {
        #pragma unroll
        for (int r = 0; r < 4; r++) Qp[(size_t)(row + r) * 512 + col] = bfs(vk[r]);
      } else {
        #pragma unroll
        for (int r = 0; r < 4; r++) Kp[(size_t)(row + r) * 512 + col] = bfs(vk[r]);
        f32x4 vv = accV[mi][ni];
        int bb = row >> 11, j = row & 2047;
        int hh = col >> 6, d = col & 63;
        uint2 o;
        o.x = pk2(vv[0], vv[1]);
        o.y = pk2(vv[2], vv[3]);
        *(uint2*)&Vtp[((size_t)((bb * 8 + hh) * 64 + d)) * 2048 + j] = o;
      }
    }
  }
}

// -------- fixed-max flash attention, split-K x8, poly-in-d^2 bias ----------
// grid (128, 8, 2): x = qt*8 + split; 4 waves/block, wave = 16 q-rows
// K/V tiles register-prefetched one iteration ahead; f16 partials out.
__global__ __launch_bounds__(256, 4) void attn_kernel(
    const u16* __restrict__ Qb, const u16* __restrict__ Kb,
    const u16* __restrict__ Vt, const float* __restrict__ qc,
    const u16* __restrict__ keg, const float* __restrict__ polyc,
    u16* __restrict__ Op, float* __restrict__ Lp) {
  __shared__ u16 Kl[64 * LS];
  __shared__ u16 Vtl[64 * LS];
  __shared__ u16 Pl[64 * LS];

  const int t = threadIdx.x;
  const int w = t >> 6, l = t & 63, g = l >> 4, li = l & 15;
  const int qt = blockIdx.x >> 3, sidx = blockIdx.x & 7;
  const int h = blockIdx.y, b = blockIdx.z;

  const float c0 = polyc[h * 8 + 0], c1 = polyc[h * 8 + 1];
  const float c2 = polyc[h * 8 + 2], c3 = polyc[h * 8 + 3];
  const float c4 = polyc[h * 8 + 4], c5 = polyc[h * 8 + 5];

  const int qrow = qt * 64 + w * 16 + li;
  const size_t qg = (size_t)b * NQ + qrow;
  bf16x8 qf0 = *(const bf16x8*)&Qb[qg * 512 + h * 64 + g * 8];
  bf16x8 qf1 = *(const bf16x8*)&Qb[qg * 512 + h * 64 + 32 + g * 8];
  float qx = qc[qg * 3], qy = qc[qg * 3 + 1], qz = qc[qg * 3 + 2];
  bf16x8 qe = {};
  if (g == 0) {
    qe[0] = (short)bfs(qx);
    qe[1] = (short)bfs(qy);
    qe[2] = (short)bfs(qz);
    qe[3] = (short)bfs(qx * qx + qy * qy + qz * qz);
    qe[4] = (short)bfs(1.0f);
  }

  f32x4 oacc[4] = {};
  float lacc = 0.0f;

  const u16* Kg = Kb + (size_t)b * NK * 512 + h * 64;
  const u16* Vg = Vt + (size_t)((b * 8 + h) * 64) * 2048;
  const u16* keg_b = keg + (size_t)b * NK * 8;

  const int jb0 = sidx * (NK / NSPLIT);
  const int srow = t >> 3, sc8 = (t & 7) * 8;

  bf16x8 kr0 = *(const bf16x8*)&Kg[(size_t)(jb0 + srow) * 512 + sc8];
  bf16x8 kr1 = *(const bf16x8*)&Kg[(size_t)(jb0 + 32 + srow) * 512 + sc8];
  bf16x8 vr0 = *(const bf16x8*)&Vg[(size_t)srow * 2048 + jb0 + sc8];
  bf16x8 vr1 = *(const bf16x8*)&Vg[(size_t)(32 + srow) * 2048 + jb0 + sc8];

  for (int it = 0; it < NK / NSPLIT / 64; it++) {
    const int jbase = jb0 + it * 64;
    __syncthreads();
    *(bf16x8*)&Kl[srow * LS + sc8] = kr0;
    *(bf16x8*)&Kl[(32 + srow) * LS + sc8] = kr1;
    *(bf16x8*)&Vtl[srow * LS + sc8] = vr0;
    *(bf16x8*)&Vtl[(32 + srow) * LS + sc8] = vr1;
    __syncthreads();
    if (it + 1 < NK / NSPLIT / 64) {
      const int jn = jbase + 64;
      kr0 = *(const bf16x8*)&Kg[(size_t)(jn + srow) * 512 + sc8];
      kr1 = *(const bf16x8*)&Kg[(size_t)(jn + 32 + srow) * 512 + sc8];
      vr0 = *(const bf16x8*)&Vg[(size_t)srow * 2048 + jn + sc8];
      vr1 = *(const bf16x8*)&Vg[(size_t)(32 + srow) * 2048 + jn + sc8];
    }

    #pragma unroll
    for (int j4 = 0; j4 < 4; j4++) {
      bf16x8 ka0 = *(const bf16x8*)&Kl[(j4 * 16 + li) * LS + g * 8];
      bf16x8 ka1 = *(const bf16x8*)&Kl[(j4 * 16 + li) * LS + 32 + g * 8];
      f32x4 z = {};
      f32x4 s0 = MFMA16(ka0, qf0, z);
      f32x4 sac = MFMA16(ka1, qf1, s0);
      bf16x8 ke = {};
      if (g == 0)
        ke = *(const bf16x8*)&keg_b[(size_t)(jbase + j4 * 16 + li) * 8];
      f32x4 dac = MFMA16(ke, qe, z);

      float p[4];
      #pragma unroll
      for (int r = 0; r < 4; r++) {
        float u = fminf(dac[r], 256.0f);
        float gp = fmaf(fmaf(fmaf(fmaf(fmaf(c5, u, c4), u, c3), u, c2), u, c1), u, c0);
        p[r] = __builtin_amdgcn_exp2f(fmaf(sac[r], SC2, gp));
      }
      lacc += (p[0] + p[1]) + (p[2] + p[3]);
      uint2 pv;
      pv.x = pk2(p[0], p[1]);
      pv.y = pk2(p[2], p[3]);
      *(uint2*)&Pl[(w * 16 + li) * LS + j4 * 16 + g * 4] = pv;
    }

    bf16x8 pf0 = *(const bf16x8*)&Pl[(w * 16 + li) * LS + g * 8];
    bf16x8 pf1 = *(const bf16x8*)&Pl[(w * 16 + li) * LS + 32 + g * 8];
    #pragma unroll
    for (int dt = 0; dt < 4; dt++) {
      bf16x8 v0 = *(const bf16x8*)&Vtl[(dt * 16 + li) * LS + g * 8];
      bf16x8 v1 = *(const bf16x8*)&Vtl[(dt * 16 + li) * LS + 32 + g * 8];
      oacc[dt] = MFMA16(pf0, v0, oacc[dt]);
      oacc[dt] = MFMA16(pf1, v1, oacc[dt]);
    }
  }

  float lf = lacc;
  lf += __shfl_xor(lf, 16);
  lf += __shfl_xor(lf, 32);

  // f16 partials (halves Opart HBM traffic; |O_s|<~10 fits f16 comfortably)
  const size_t obase =
      ((size_t)(sidx * 16 + b * 8 + h) * 1024 + qt * 64 + w * 16) * 64;
  #pragma unroll
  for (int dt = 0; dt < 4; dt++)
    #pragma unroll
    for (int r = 0; r < 4; r++)
      Op[obase + (size_t)(4 * g + r) * 64 + dt * 16 + li] =
          __half_as_ushort(__float2half(oacc[dt][r]));
  if (g == 0)
    Lp[(size_t)(sidx * 16 + b * 8 + h) * 1024 + qt * 64 + w * 16 + li] = lf;
}

// ------------- combine f16 split partials, normalize, write bf16 AO --------
__global__ __launch_bounds__(256) void combine_kernel(const u16* __restrict__ Op,
                                                      const float* __restrict__ Lp,
                                                      u16* __restrict__ AOb) {
  int tid = blockIdx.x * 256 + threadIdx.x;   // 262144 total
  int d4 = tid & 15, rh = tid >> 4;
  int bh = rh >> 10, qrow = rh & 1023;
  float o0 = 0, o1 = 0, o2 = 0, o3 = 0;
  float lsum = 0.0f;
  #pragma unroll
  for (int s = 0; s < NSPLIT; s++) {
    uint2 v = *(const uint2*)&Op[((size_t)(s * 16 + bh) * 1024 + qrow) * 64 + d4 * 4];
    __half2 h01 = __builtin_bit_cast(__half2, v.x);
    __half2 h23 = __builtin_bit_cast(__half2, v.y);
    o0 += __low2float(h01); o1 += __high2float(h01);
    o2 += __low2float(h23); o3 += __high2float(h23);
    lsum += Lp[(size_t)(s * 16 + bh) * 1024 + qrow];
  }
  float inv = __builtin_amdgcn_rcpf(lsum);
  uint2 pk;
  pk.x = pk2(o0 * inv, o1 * inv);
  pk.y = pk2(o2 * inv, o3 * inv);
  *(uint2*)&AOb[((size_t)(bh >> 3) * NQ + qrow) * 512 + (bh & 7) * 64 + d4 * 4] = pk;
}

// ---------------- bf16 MFMA GEMM (Wo pass), TM=32, fp32 out ----------------
__global__ __launch_bounds__(256) void gemm_wo(const u16* __restrict__ A,
                                               const u16* __restrict__ Bt,
                                               float* __restrict__ C) {
  __shared__ u16 As[32 * LS];
  __shared__ u16 Bs[64 * LS];
  const int t = threadIdx.x;
  const int w = t >> 6, l = t & 63, g = l >> 4, li = l & 15;
  const int m0 = blockIdx.x * 32, n0 = blockIdx.y * 64;
  const int ms = (w & 1) * 16, ns = (w >> 1) * 32;
  f32x4 acc[2] = {};
  for (int kt = 0; kt < 512; kt += 64) {
    bf16x8 av, bv[2];
    {
      int r = t >> 3, c8 = (t & 7) * 8;
      av = *(const bf16x8*)&A[(size_t)(m0 + r) * 512 + kt + c8];
    }
    #pragma unroll
    for (int p = 0; p < 2; p++) {
      int f = p * 256 + t, r = f >> 3, c8 = (f & 7) * 8;
      bv[p] = *(const bf16x8*)&Bt[(size_t)(n0 + r) * 512 + kt + c8];
    }
    __syncthreads();
    {
      int r = t >> 3, c8 = (t & 7) * 8;
      *(bf16x8*)&As[r * LS + c8] = av;
    }
    #pragma unroll
    for (int p = 0; p < 2; p++) {
      int f = p * 256 + t, r = f >> 3, c8 = (f & 7) * 8;
      *(bf16x8*)&Bs[r * LS + c8] = bv[p];
    }
    __syncthreads();
    #pragma unroll
    for (int ks = 0; ks < 2; ks++) {
      bf16x8 af = *(const bf16x8*)&As[(ms + li) * LS + ks * 32 + g * 8];
      bf16x8 b0 = *(const bf16x8*)&Bs[(ns + li) * LS + ks * 32 + g * 8];
      bf16x8 b1 = *(const bf16x8*)&Bs[(ns + 16 + li) * LS + ks * 32 + g * 8];
      acc[0] = MFMA16(af, b0, acc[0]);
      acc[1] = MFMA16(af, b1, acc[1]);
    }
  }
  #pragma unroll
  for (int ni = 0; ni < 2; ni++) {
    f32x4 v = acc[ni];
    int row = m0 + ms + 4 * g;
    int col = n0 + ns + ni * 16 + li;
    #pragma unroll
    for (int r = 0; r < 4; r++) C[(size_t)(row + r) * 512 + col] = v[r];
  }
}

extern "C" void kernel_launch(void* const* d_in, const int* in_sizes, int n_in,
                              void* d_out, int out_size, void* d_ws, size_t ws_size,
                              hipStream_t stream) {
  const float* q_in      = (const float*)d_in[0];
  const float* kv_in     = (const float*)d_in[1];
  const float* q_coords  = (const float*)d_in[2];
  const float* kv_coords = (const float*)d_in[3];
  const float* Wq        = (const float*)d_in[4];
  const float* Wk        = (const float*)d_in[5];
  const float* Wv        = (const float*)d_in[6];
  const float* Wo        = (const float*)d_in[7];
  const float* W1        = (const float*)d_in[8];
  const float* b1        = (const float*)d_in[9];
  const float* W2        = (const float*)d_in[10];
  const float* b2        = (const float*)d_in[11];

  char* p = (char*)d_ws;
  u16* Wqt  = (u16*)p; p += (size_t)512 * 512 * 2;
  u16* Wkt  = (u16*)p; p += (size_t)512 * 512 * 2;
  u16* Wvt  = (u16*)p; p += (size_t)512 * 512 * 2;
  u16* Wot  = (u16*)p; p += (size_t)512 * 512 * 2;
  u16* qb   = (u16*)p; p += (size_t)2048 * 512 * 2;
  u16* kvb  = (u16*)p; p += (size_t)4096 * 512 * 2;
  u16* Qp   = (u16*)p; p += (size_t)2048 * 512 * 2;
  u16* Kp   = (u16*)p; p += (size_t)4096 * 512 * 2;
  u16* Vtp  = (u16*)p; p += (size_t)4096 * 512 * 2;
  u16* AOb  = (u16*)p; p += (size_t)2048 * 512 * 2;
  u16* keg  = (u16*)p; p += (size_t)4096 * 8 * 2;
  float* polyc = (float*)p; p += (size_t)64 * 4;
  p = (char*)(((size_t)p + 255) & ~(size_t)255);
  u16* Opart = (u16*)p; p += (size_t)NSPLIT * 16 * 1024 * 64 * 2;
  float* Lpart = (float*)p; p += (size_t)NSPLIT * 16 * 1024 * 4;

  setup_kernel<<<1809, 256, 0, stream>>>(Wq, Wk, Wv, Wo, Wqt, Wkt, Wvt, Wot,
                                         W1, b1, W2, b2, polyc, kv_coords, keg,
                                         q_in, kv_in, qb, kvb);
  gemm_qkv<<<dim3(96, 8), 256, 0, stream>>>(qb, kvb, Wqt, Wkt, Wvt,
                                            Qp, Kp, Vtp);
  attn_kernel<<<dim3(128, 8, 2), 256, 0, stream>>>(Qp, Kp, Vtp, q_coords, keg,
                                                   polyc, Opart, Lpart);
  combine_kernel<<<1024, 256, 0, stream>>>(Opart, Lpart, AOb);
  gemm_wo<<<dim3(64, 8), 256, 0, stream>>>(AOb, Wot, (float*)d_out);
}